// Round 2
// baseline (317.015 us; speedup 1.0000x reference)
//
#include <hip/hip_runtime.h>

#define EPS_DENOM 1e-8f

// One wave (64 lanes) per keypoint. 4 waves per 256-thread block.
__global__ __launch_bounds__(256) void corr_main_kernel(
    const float* __restrict__ src, const float* __restrict__ tgt,
    const int* __restrict__ skps, const int* __restrict__ tkps,
    const int* __restrict__ valid, const int* __restrict__ psz_p,
    float* __restrict__ ws,
    int B, int H, int W, int D, int N)
{
    const int wave = threadIdx.x >> 6;
    const int lane = threadIdx.x & 63;
    const int kp = blockIdx.x * 4 + wave;
    const int nkp = B * N;
    if (kp >= nkp) return;

    const int b = kp / N;
    const int n = kp - b * N;
    const int ps = psz_p[0];

    // kps layout (B,N,2): [...,0]=x (W index), [...,1]=y (H index)
    int sx = skps[(size_t)kp * 2 + 0] / ps;
    int sy = skps[(size_t)kp * 2 + 1] / ps;
    int tx = tkps[(size_t)kp * 2 + 0] / ps;
    int ty = tkps[(size_t)kp * 2 + 1] / ps;
    sx = min(max(sx, 0), W - 1);
    sy = min(max(sy, 0), H - 1);
    tx = min(max(tx, 0), W - 1);
    ty = min(max(ty, 0), H - 1);

    const float4* __restrict__ srow =
        (const float4*)(src + (((size_t)b * H + sy) * W + sx) * (size_t)D);
    const float4* __restrict__ trow =
        (const float4*)(tgt + (((size_t)b * H + ty) * W + tx) * (size_t)D);

    float dot = 0.f, s2 = 0.f, t2 = 0.f;
    const int nv4 = D >> 2;            // 192 float4 per row
    for (int i = lane; i < nv4; i += 64) {
        float4 a = srow[i];
        float4 c = trow[i];
        dot += a.x * c.x + a.y * c.y + a.z * c.z + a.w * c.w;
        s2  += a.x * a.x + a.y * a.y + a.z * a.z + a.w * a.w;
        t2  += c.x * c.x + c.y * c.y + c.z * c.z + c.w * c.w;
    }

    // 64-lane butterfly reduce (wave = 64 on CDNA)
    #pragma unroll
    for (int off = 32; off; off >>= 1) {
        dot += __shfl_xor(dot, off, 64);
        s2  += __shfl_xor(s2,  off, 64);
        t2  += __shfl_xor(t2,  off, 64);
    }

    if (lane == 0) {
        float denom = fmaxf(sqrtf(s2) * sqrtf(t2), EPS_DENOM);
        float cosv  = dot / denom;
        float v     = (valid[kp] != 0) ? 1.0f : 0.0f;
        ws[(size_t)kp * 2 + 0] = (1.0f - cosv) * v;
        ws[(size_t)kp * 2 + 1] = v;
    }
}

// Single 256-thread block reduces the 4096 (loss, valid) pairs.
__global__ __launch_bounds__(256) void corr_final_kernel(
    const float* __restrict__ ws, float* __restrict__ out, int nkp)
{
    float tl = 0.f, tv = 0.f;
    for (int i = threadIdx.x; i < nkp; i += 256) {
        tl += ws[(size_t)i * 2 + 0];
        tv += ws[(size_t)i * 2 + 1];
    }
    #pragma unroll
    for (int off = 32; off; off >>= 1) {
        tl += __shfl_xor(tl, off, 64);
        tv += __shfl_xor(tv, off, 64);
    }
    __shared__ float sl[4], sv[4];
    const int wave = threadIdx.x >> 6;
    const int lane = threadIdx.x & 63;
    if (lane == 0) { sl[wave] = tl; sv[wave] = tv; }
    __syncthreads();
    if (threadIdx.x == 0) {
        float L = sl[0] + sl[1] + sl[2] + sl[3];
        float V = sv[0] + sv[1] + sv[2] + sv[3];
        out[0] = L / fmaxf(V, 1.0f);
    }
}

extern "C" void kernel_launch(void* const* d_in, const int* in_sizes, int n_in,
                              void* d_out, int out_size, void* d_ws, size_t ws_size,
                              hipStream_t stream) {
    const float* src   = (const float*)d_in[0];
    const float* tgt   = (const float*)d_in[1];
    const int*   skps  = (const int*)d_in[2];
    const int*   tkps  = (const int*)d_in[3];
    const int*   valid = (const int*)d_in[4];
    const int*   psz   = (const int*)d_in[5];
    float* out = (float*)d_out;
    float* ws  = (float*)d_ws;

    // Problem geometry (fixed by setup_inputs): B=16, H=W=64, D=768, N=256
    const int B = 16, H = 64, W = 64, D = 768, N = 256;
    const int nkp = B * N;                 // 4096
    const int blocks = (nkp + 3) / 4;      // 4 waves (keypoints) per block

    corr_main_kernel<<<blocks, 256, 0, stream>>>(src, tgt, skps, tkps, valid, psz,
                                                 ws, B, H, W, D, N);
    corr_final_kernel<<<1, 256, 0, stream>>>(ws, out, nkp);
}